// Round 3
// baseline (1523.623 us; speedup 1.0000x reference)
//
#include <hip/hip_runtime.h>
#include <hip/hip_bf16.h>
#include <stdint.h>

#define B_ 4096
#define D_ 512
#define H_ 2048
#define NS_ 16

typedef __bf16 bf16x8 __attribute__((ext_vector_type(8)));
typedef float f32x4 __attribute__((ext_vector_type(4)));
typedef short short4v __attribute__((ext_vector_type(4)));
typedef __attribute__((address_space(3))) const bf16x8* lds_frag_p;

__device__ __forceinline__ short f2bf(float f) {
  union { float f; uint32_t u; } c; c.f = f;
  uint32_t u = c.u;
  return (short)((u + 0x7fffu + ((u >> 16) & 1u)) >> 16);
}

__device__ __forceinline__ float tanh_fast(float x) {
  float e = __expf(2.0f * x);
  return 1.0f - 2.0f / (e + 1.0f);   // exp overflow -> 1, underflow -> -1 : safe
}

__device__ __forceinline__ void gload16(const void* g, void* l) {
  __builtin_amdgcn_global_load_lds((const __attribute__((address_space(1))) void*)g,
                                   (__attribute__((address_space(3))) void*)l,
                                   16, 0, 0);
}

// ===========================================================================
// Fused RNN step GEMM, 256x256 tile, 8 waves (2Mx4N), BK=32, 4-deep LDS ring,
// counted vmcnt(8), m201-style 2-barrier phases, T2 XOR swizzle, T5 setprio.
//   [h_next | out_t] = tanh(xproj + h @ Wh) | (h @ Wout + bout)
// A  = h_t     [4096][2048] bf16 row-major
// Bt = Wcat^T  [2560][2048] bf16 row-major (rows = output cols)
// ===========================================================================
__global__ __launch_bounds__(512, 2) void gemm256_fused(
    const short* __restrict__ A, const short* __restrict__ Bt, int K,
    const float* __restrict__ xproj, const float* __restrict__ bias,
    float* __restrict__ outf, short* __restrict__ outh, int tout, int gridN)
{
  __shared__ short lds[65536];                // 128 KB: 4 bufs x (A 8192 + B 8192 shorts)
  const int tid = threadIdx.x, lane = tid & 63, wid = tid >> 6;
  const int wm = wid >> 2, wn = wid & 3;      // 2 x 4 wave grid, wave tile 128x64

  // XCD-aware bijective swizzle (gridDim.x % 8 == 0)
  const int nwg = gridDim.x;
  const int cpx = nwg >> 3;
  const int swz = ((int)blockIdx.x & 7) * cpx + ((int)blockIdx.x >> 3);
  const int tm = swz / gridN, tn = swz % gridN;
  const int row0 = tm * 256, col0 = tn * 256;

  const int NT = K >> 5;                      // K-tiles of 32

  // ---- staging: global source carries the inverse XOR swizzle (rule 21) ----
  // Linear LDS dest: row r at element r*32, 8-short group p = lane&3.
  // Stored content at phys group p = logical k-group p ^ ((r>>1)&3).
  const int rA0 = wid * 32 + (lane >> 2);
  const int rA1 = rA0 + 16;
  const int sl = lane & 3;
  const short* gA0 = A  + (size_t)(row0 + rA0) * K + ((sl ^ ((rA0 >> 1) & 3)) << 3);
  const short* gA1 = A  + (size_t)(row0 + rA1) * K + ((sl ^ ((rA1 >> 1) & 3)) << 3);
  const short* gB0 = Bt + (size_t)(col0 + rA0) * K + ((sl ^ ((rA0 >> 1) & 3)) << 3);
  const short* gB1 = Bt + (size_t)(col0 + rA1) * K + ((sl ^ ((rA1 >> 1) & 3)) << 3);

  // ---- fragment read offsets (element units, swizzled) ----
  const int rr = lane & 15, s4 = lane >> 4;
  int offA[8], offB[4];
#pragma unroll
  for (int m = 0; m < 8; ++m) {
    int r = wm * 128 + m * 16 + rr;
    offA[m] = r * 32 + ((s4 ^ ((r >> 1) & 3)) << 3);
  }
#pragma unroll
  for (int n = 0; n < 4; ++n) {
    int r = wn * 64 + n * 16 + rr;
    offB[n] = 8192 + r * 32 + ((s4 ^ ((r >> 1) & 3)) << 3);
  }

  f32x4 acc[8][4];
#pragma unroll
  for (int m = 0; m < 8; ++m)
#pragma unroll
    for (int n = 0; n < 4; ++n)
      acc[m][n] = (f32x4){0.f, 0.f, 0.f, 0.f};

  auto stageA = [&](int kt) {
    int d = (kt & 3) * 16384 + wid * 1024;
    gload16(gA0 + (size_t)kt * 32, &lds[d]);
    gload16(gA1 + (size_t)kt * 32, &lds[d + 512]);
  };
  auto stageB = [&](int kt) {
    int d = (kt & 3) * 16384 + 8192 + wid * 1024;
    gload16(gB0 + (size_t)kt * 32, &lds[d]);
    gload16(gB1 + (size_t)kt * 32, &lds[d + 512]);
  };

  // prologue: stage tiles 0,1,2 (12 loads); tile 0 = oldest 4
  stageA(0); stageB(0);
  stageA(1); stageB(1);
  stageA(2); stageB(2);
  asm volatile("s_waitcnt vmcnt(8)" ::: "memory");   // tile 0 landed (own loads)
  __builtin_amdgcn_s_barrier();                      // all waves' tile-0 landed

  bf16x8 a[4], b[4];
  for (int kt = 0; kt < NT; ++kt) {
    const int bb = (kt & 3) * 16384;
    const bool st = (kt < NT - 3);
    // ---------------- phase A: m0-3 x n0-3 ----------------
#pragma unroll
    for (int m = 0; m < 4; ++m) a[m] = *(lds_frag_p)&lds[bb + offA[m]];
#pragma unroll
    for (int n = 0; n < 4; ++n) b[n] = *(lds_frag_p)&lds[bb + offB[n]];
    if (st) stageA(kt + 3);
    __builtin_amdgcn_sched_barrier(0);
    __builtin_amdgcn_s_barrier();
    asm volatile("s_waitcnt lgkmcnt(0)" ::: "memory");
    __builtin_amdgcn_sched_barrier(0);
    __builtin_amdgcn_s_setprio(1);
#pragma unroll
    for (int m = 0; m < 4; ++m)
#pragma unroll
      for (int n = 0; n < 4; ++n)
        acc[m][n] = __builtin_amdgcn_mfma_f32_16x16x32_bf16(a[m], b[n], acc[m][n], 0, 0, 0);
    __builtin_amdgcn_s_setprio(0);
    __builtin_amdgcn_s_barrier();
    // ---------------- phase B: m4-7 x n0-3 (b reused in regs) ----------------
#pragma unroll
    for (int m = 0; m < 4; ++m) a[m] = *(lds_frag_p)&lds[bb + offA[4 + m]];
    if (st) {
      stageB(kt + 3);
      asm volatile("s_waitcnt vmcnt(8)" ::: "memory");   // tile kt+1 landed
    } else if (kt == NT - 3) {
      asm volatile("s_waitcnt vmcnt(4)" ::: "memory");
    } else if (kt == NT - 2) {
      asm volatile("s_waitcnt vmcnt(0)" ::: "memory");
    }
    __builtin_amdgcn_sched_barrier(0);
    __builtin_amdgcn_s_barrier();
    asm volatile("s_waitcnt lgkmcnt(0)" ::: "memory");
    __builtin_amdgcn_sched_barrier(0);
    __builtin_amdgcn_s_setprio(1);
#pragma unroll
    for (int m = 0; m < 4; ++m)
#pragma unroll
      for (int n = 0; n < 4; ++n)
        acc[4 + m][n] = __builtin_amdgcn_mfma_f32_16x16x32_bf16(a[m], b[n], acc[4 + m][n], 0, 0, 0);
    __builtin_amdgcn_s_setprio(0);
    __builtin_amdgcn_s_barrier();
  }

  // ---- epilogue: C/D layout col = lane&15, row = (lane>>4)*4 + reg ----
  const int rb = row0 + wm * 128 + ((lane >> 4) << 2);
  const int cb = col0 + wn * 64 + (lane & 15);
#pragma unroll
  for (int m = 0; m < 8; ++m) {
#pragma unroll
    for (int n = 0; n < 4; ++n) {
      const int col = cb + n * 16;
#pragma unroll
      for (int r = 0; r < 4; ++r) {
        const int row = rb + m * 16 + r;
        float v = acc[m][n][r];
        if (col < H_) {
          float x = xproj[(size_t)row * H_ + col];
          outh[(size_t)row * H_ + col] = f2bf(tanh_fast(x + v));
        } else {
          int oc = col - H_;
          outf[(size_t)row * (NS_ * D_) + tout * D_ + oc] = v + bias[oc];
        }
      }
    }
  }
}

// ---------------------------------------------------------------------------
// 128-tile GEMM (round-1 structure) for xproj (EPI 0) and final out (EPI 2).
// ---------------------------------------------------------------------------
template<int BM, int BN, int EPI>
__global__ __launch_bounds__(256, 2) void gemm_bt(
    const short* __restrict__ A, const short* __restrict__ Bt, int K,
    const float* __restrict__ xproj, const float* __restrict__ bias,
    float* __restrict__ outf, short* __restrict__ outh, int ldN, int tout)
{
  constexpr int WM = BM / 2, WN = BN / 2;
  constexpr int RM = WM / 16, RN = WN / 16;
  __shared__ short lds[2][(BM + BN) * 32];
  const int tid = threadIdx.x, lane = tid & 63, wid = tid >> 6;
  const int wm = wid >> 1, wn = wid & 1;
  const int row0 = blockIdx.y * BM, col0 = blockIdx.x * BN;
  const short* Ag = A + (size_t)row0 * K;
  const short* Bg = Bt + (size_t)col0 * K;

  f32x4 acc[RM][RN];
#pragma unroll
  for (int m = 0; m < RM; ++m)
#pragma unroll
    for (int n = 0; n < RN; ++n)
      acc[m][n] = (f32x4){0.f, 0.f, 0.f, 0.f};

  const int nt = K >> 5;

  auto stage = [&](int kt, int buf) {
    const short* ga = Ag + (kt << 5);
#pragma unroll
    for (int i = 0; i < BM * 4; i += 256) {
      int slot = i + tid;
      gload16(ga + (size_t)(slot >> 2) * K + ((slot & 3) << 3), &lds[buf][slot * 8]);
    }
    const short* gb = Bg + (kt << 5);
#pragma unroll
    for (int i = 0; i < BN * 4; i += 256) {
      int slot = i + tid;
      gload16(gb + (size_t)(slot >> 2) * K + ((slot & 3) << 3),
              &lds[buf][BM * 32 + slot * 8]);
    }
  };

  stage(0, 0);
  __syncthreads();
  int cur = 0;
  const int kq = (lane >> 4) << 3;
  const int rr = lane & 15;
  for (int kt = 0; kt < nt; ++kt) {
    if (kt + 1 < nt) stage(kt + 1, cur ^ 1);
    const short* la = &lds[cur][(wm * WM) * 32];
    const short* lb = &lds[cur][BM * 32 + (wn * WN) * 32];
    bf16x8 a[RM], b[RN];
#pragma unroll
    for (int m = 0; m < RM; ++m)
      a[m] = *(const bf16x8*)(la + (m * 16 + rr) * 32 + kq);
#pragma unroll
    for (int n = 0; n < RN; ++n)
      b[n] = *(const bf16x8*)(lb + (n * 16 + rr) * 32 + kq);
#pragma unroll
    for (int m = 0; m < RM; ++m)
#pragma unroll
      for (int n = 0; n < RN; ++n)
        acc[m][n] = __builtin_amdgcn_mfma_f32_16x16x32_bf16(a[m], b[n], acc[m][n], 0, 0, 0);
    __syncthreads();
    cur ^= 1;
  }

  const int rb = row0 + wm * WM + ((lane >> 4) << 2);
  const int cb = col0 + wn * WN + (lane & 15);
#pragma unroll
  for (int m = 0; m < RM; ++m) {
#pragma unroll
    for (int n = 0; n < RN; ++n) {
      const int col = cb + n * 16;
#pragma unroll
      for (int r = 0; r < 4; ++r) {
        const int row = rb + m * 16 + r;
        float v = acc[m][n][r];
        if (EPI == 0) {
          outf[(size_t)row * ldN + col] = v + bias[col];
        } else {
          outf[(size_t)row * (NS_ * D_) + tout * D_ + col] = v + bias[col];
        }
      }
    }
  }
}

// in [R][C] fp32  ->  out [C][R] bf16
__global__ void transpose_cvt(const float* __restrict__ in, short* __restrict__ out,
                              int R, int C) {
  __shared__ float tile[32][33];
  const int tx = threadIdx.x & 31, ty = threadIdx.x >> 5;
  const int c0 = blockIdx.x * 32, r0 = blockIdx.y * 32;
#pragma unroll
  for (int i = 0; i < 32; i += 8)
    tile[ty + i][tx] = in[(size_t)(r0 + ty + i) * C + c0 + tx];
  __syncthreads();
#pragma unroll
  for (int i = 0; i < 32; i += 8)
    out[(size_t)(c0 + ty + i) * R + r0 + tx] = f2bf(tile[tx][ty + i]);
}

__global__ void cvt_bf16_k(const float4* __restrict__ in, short4v* __restrict__ out, int n4) {
  int i = blockIdx.x * 256 + threadIdx.x;
  if (i >= n4) return;
  float4 v = in[i];
  short4v o;
  o[0] = f2bf(v.x); o[1] = f2bf(v.y); o[2] = f2bf(v.z); o[3] = f2bf(v.w);
  out[i] = o;
}

__global__ void tanh_h0_k(const float4* __restrict__ xp, short4v* __restrict__ h, int n4) {
  int i = blockIdx.x * 256 + threadIdx.x;
  if (i >= n4) return;
  float4 v = xp[i];
  short4v o;
  o[0] = f2bf(tanh_fast(v.x)); o[1] = f2bf(tanh_fast(v.y));
  o[2] = f2bf(tanh_fast(v.z)); o[3] = f2bf(tanh_fast(v.w));
  h[i] = o;
}

extern "C" void kernel_launch(void* const* d_in, const int* in_sizes, int n_in,
                              void* d_out, int out_size, void* d_ws, size_t ws_size,
                              hipStream_t stream) {
  const float* z    = (const float*)d_in[0];
  const float* Wx   = (const float*)d_in[1];
  const float* Wh   = (const float*)d_in[2];
  const float* bh   = (const float*)d_in[3];
  const float* Wout = (const float*)d_in[4];
  const float* bout = (const float*)d_in[5];
  float* out = (float*)d_out;

  // workspace layout
  short* zb    = (short*)d_ws;                     // B*D bf16
  short* WxT   = zb + (size_t)B_ * D_;             // [H][D]
  short* WcatT = WxT + (size_t)H_ * D_;            // [H+D][H]  (WhT then WoutT)
  short* WoutT = WcatT + (size_t)H_ * H_;
  short* h0    = WcatT + (size_t)(H_ + D_) * H_;   // [B][H] bf16
  short* h1    = h0 + (size_t)B_ * H_;
  float* xproj = (float*)(h1 + (size_t)B_ * H_);   // [B][H] fp32

  cvt_bf16_k<<<(B_ * D_ / 4 + 255) / 256, 256, 0, stream>>>((const float4*)z, (short4v*)zb, B_ * D_ / 4);
  transpose_cvt<<<dim3(H_ / 32, D_ / 32), 256, 0, stream>>>(Wx, WxT, D_, H_);
  transpose_cvt<<<dim3(H_ / 32, H_ / 32), 256, 0, stream>>>(Wh, WcatT, H_, H_);
  transpose_cvt<<<dim3(D_ / 32, H_ / 32), 256, 0, stream>>>(Wout, WoutT, H_, D_);

  // xproj = z @ Wx + bh
  gemm_bt<128, 128, 0><<<dim3(H_ / 128, B_ / 128), 256, 0, stream>>>(
      zb, WxT, D_, nullptr, bh, xproj, nullptr, H_, 0);
  // h1 = tanh(xproj)
  tanh_h0_k<<<(B_ * H_ / 4 + 255) / 256, 256, 0, stream>>>((const float4*)xproj, (short4v*)h0, B_ * H_ / 4);

  short* hb[2] = {h0, h1};
  for (int t = 1; t <= 15; ++t) {
    const short* hp = hb[(t - 1) & 1];
    short* hn = hb[t & 1];
    // fused: [h_{t+1} | out_{t-1}] = h_t @ [Wh | Wout], 16x10 = 160 blocks
    gemm256_fused<<<160, 512, 0, stream>>>(
        hp, WcatT, H_, xproj, bout, out, hn, t - 1, 10);
  }
  // out_15 = h16 @ Wout + bout
  gemm_bt<128, 64, 2><<<dim3(D_ / 64, B_ / 128), 256, 0, stream>>>(
      hb[1], WoutT, H_, nullptr, bout, out, nullptr, 0, 15);
}

// Round 4
// 1508.038 us; speedup vs baseline: 1.0103x; 1.0103x over previous
//
#include <hip/hip_runtime.h>
#include <hip/hip_bf16.h>
#include <stdint.h>

#define B_ 4096
#define D_ 512
#define H_ 2048
#define NS_ 16

typedef __bf16 bf16x8 __attribute__((ext_vector_type(8)));
typedef float f32x4 __attribute__((ext_vector_type(4)));
typedef short short4v __attribute__((ext_vector_type(4)));
typedef __attribute__((address_space(3))) const bf16x8* lds_frag_p;

__device__ __forceinline__ short f2bf(float f) {
  union { float f; uint32_t u; } c; c.f = f;
  uint32_t u = c.u;
  return (short)((u + 0x7fffu + ((u >> 16) & 1u)) >> 16);
}

__device__ __forceinline__ float tanh_fast(float x) {
  float e = __expf(2.0f * x);
  return 1.0f - 2.0f / (e + 1.0f);   // exp overflow -> 1, underflow -> -1 : safe
}

__device__ __forceinline__ void gload16(const void* g, void* l) {
  __builtin_amdgcn_global_load_lds((const __attribute__((address_space(1))) void*)g,
                                   (__attribute__((address_space(3))) void*)l,
                                   16, 0, 0);
}

// ===========================================================================
// Fused RNN step GEMM, 256x256 tile, 8 waves (2Mx4N), BK=32, 4-deep LDS ring.
// SINGLE barrier + single counted vmcnt per K-tile; stages issued at TOP of
// tile body (max age before any possible drain); compiler schedules
// ds_read<->MFMA overlap via its own fine-grained lgkmcnt.
//   [h_next | out_t] = tanh(xproj + h @ Wh) | (h @ Wout + bout)
// A  = h_t     [4096][2048] bf16 row-major
// Bt = Wcat^T  [2560][2048] bf16 row-major (rows = output cols)
// ===========================================================================
__global__ __launch_bounds__(512, 2) void gemm256_fused(
    const short* __restrict__ A, const short* __restrict__ Bt, int K,
    const float* __restrict__ xproj, const float* __restrict__ bias,
    float* __restrict__ outf, short* __restrict__ outh, int tout, int gridN)
{
  __shared__ short lds[65536];                // 128 KB: 4 bufs x (A 8192 + B 8192 shorts)
  const int tid = threadIdx.x, lane = tid & 63, wid = tid >> 6;
  const int wm = wid >> 2, wn = wid & 3;      // 2 x 4 wave grid, wave tile 128x64

  // XCD-aware bijective swizzle (gridDim.x % 8 == 0)
  const int nwg = gridDim.x;
  const int cpx = nwg >> 3;
  const int swz = ((int)blockIdx.x & 7) * cpx + ((int)blockIdx.x >> 3);
  const int tm = swz / gridN, tn = swz % gridN;
  const int row0 = tm * 256, col0 = tn * 256;

  const int NT = K >> 5;                      // K-tiles of 32

  // ---- staging: global source carries the inverse XOR swizzle (rule 21) ----
  const int rA0 = wid * 32 + (lane >> 2);
  const int rA1 = rA0 + 16;
  const int sl = lane & 3;
  const short* gA0 = A  + (size_t)(row0 + rA0) * K + ((sl ^ ((rA0 >> 1) & 3)) << 3);
  const short* gA1 = A  + (size_t)(row0 + rA1) * K + ((sl ^ ((rA1 >> 1) & 3)) << 3);
  const short* gB0 = Bt + (size_t)(col0 + rA0) * K + ((sl ^ ((rA0 >> 1) & 3)) << 3);
  const short* gB1 = Bt + (size_t)(col0 + rA1) * K + ((sl ^ ((rA1 >> 1) & 3)) << 3);

  // ---- fragment read offsets (element units, swizzled) ----
  const int rr = lane & 15, s4 = lane >> 4;
  int offA[8], offB[4];
#pragma unroll
  for (int m = 0; m < 8; ++m) {
    int r = wm * 128 + m * 16 + rr;
    offA[m] = r * 32 + ((s4 ^ ((r >> 1) & 3)) << 3);
  }
#pragma unroll
  for (int n = 0; n < 4; ++n) {
    int r = wn * 64 + n * 16 + rr;
    offB[n] = 8192 + r * 32 + ((s4 ^ ((r >> 1) & 3)) << 3);
  }

  f32x4 acc[8][4];
#pragma unroll
  for (int m = 0; m < 8; ++m)
#pragma unroll
    for (int n = 0; n < 4; ++n)
      acc[m][n] = (f32x4){0.f, 0.f, 0.f, 0.f};

  auto stageA = [&](int kt) {
    int d = (kt & 3) * 16384 + wid * 1024;
    gload16(gA0 + (size_t)kt * 32, &lds[d]);
    gload16(gA1 + (size_t)kt * 32, &lds[d + 512]);
  };
  auto stageB = [&](int kt) {
    int d = (kt & 3) * 16384 + 8192 + wid * 1024;
    gload16(gB0 + (size_t)kt * 32, &lds[d]);
    gload16(gB1 + (size_t)kt * 32, &lds[d + 512]);
  };

  // prologue: stage tiles 0,1,2 (12 loads)
  stageA(0); stageB(0);
  stageA(1); stageB(1);
  stageA(2); stageB(2);
  asm volatile("s_waitcnt vmcnt(8)" ::: "memory");   // tile 0 landed (own loads)
  __builtin_amdgcn_s_barrier();                      // all waves' tile-0 landed

  for (int kt = 0; kt < NT; ++kt) {
    const int bb = (kt & 3) * 16384;
    // top: issue next stage first (max age before this tile's trailing barrier)
    if (kt < NT - 3) { stageA(kt + 3); stageB(kt + 3); }

    // read all 12 fragments; compiler inserts fine-grained lgkmcnt before MFMAs
    bf16x8 a[8], b[4];
#pragma unroll
    for (int m = 0; m < 8; ++m) a[m] = *(lds_frag_p)&lds[bb + offA[m]];
#pragma unroll
    for (int n = 0; n < 4; ++n) b[n] = *(lds_frag_p)&lds[bb + offB[n]];

#pragma unroll
    for (int m = 0; m < 8; ++m)
#pragma unroll
      for (int n = 0; n < 4; ++n)
        acc[m][n] = __builtin_amdgcn_mfma_f32_16x16x32_bf16(a[m], b[n], acc[m][n], 0, 0, 0);

    // end of tile: counted wait for tile kt+1, then the single barrier
    if (kt < NT - 3) {
      asm volatile("s_waitcnt vmcnt(8)" ::: "memory");
    } else if (kt == NT - 3) {
      asm volatile("s_waitcnt vmcnt(4)" ::: "memory");
    } else if (kt == NT - 2) {
      asm volatile("s_waitcnt vmcnt(0)" ::: "memory");
    }
    if (kt < NT - 1) __builtin_amdgcn_s_barrier();
  }

  // ---- epilogue: C/D layout col = lane&15, row = (lane>>4)*4 + reg ----
  const int rb = row0 + wm * 128 + ((lane >> 4) << 2);
  const int cb = col0 + wn * 64 + (lane & 15);
#pragma unroll
  for (int m = 0; m < 8; ++m) {
#pragma unroll
    for (int n = 0; n < 4; ++n) {
      const int col = cb + n * 16;
#pragma unroll
      for (int r = 0; r < 4; ++r) {
        const int row = rb + m * 16 + r;
        float v = acc[m][n][r];
        if (col < H_) {
          float x = xproj[(size_t)row * H_ + col];
          outh[(size_t)row * H_ + col] = f2bf(tanh_fast(x + v));
        } else {
          int oc = col - H_;
          outf[(size_t)row * (NS_ * D_) + tout * D_ + oc] = v + bias[oc];
        }
      }
    }
  }
}

// ---------------------------------------------------------------------------
// 128-tile GEMM (round-1 structure) for xproj (EPI 0) and final out (EPI 2).
// ---------------------------------------------------------------------------
template<int BM, int BN, int EPI>
__global__ __launch_bounds__(256, 2) void gemm_bt(
    const short* __restrict__ A, const short* __restrict__ Bt, int K,
    const float* __restrict__ xproj, const float* __restrict__ bias,
    float* __restrict__ outf, short* __restrict__ outh, int ldN, int tout)
{
  constexpr int WM = BM / 2, WN = BN / 2;
  constexpr int RM = WM / 16, RN = WN / 16;
  __shared__ short lds[2][(BM + BN) * 32];
  const int tid = threadIdx.x, lane = tid & 63, wid = tid >> 6;
  const int wm = wid >> 1, wn = wid & 1;
  const int row0 = blockIdx.y * BM, col0 = blockIdx.x * BN;
  const short* Ag = A + (size_t)row0 * K;
  const short* Bg = Bt + (size_t)col0 * K;

  f32x4 acc[RM][RN];
#pragma unroll
  for (int m = 0; m < RM; ++m)
#pragma unroll
    for (int n = 0; n < RN; ++n)
      acc[m][n] = (f32x4){0.f, 0.f, 0.f, 0.f};

  const int nt = K >> 5;

  auto stage = [&](int kt, int buf) {
    const short* ga = Ag + (kt << 5);
#pragma unroll
    for (int i = 0; i < BM * 4; i += 256) {
      int slot = i + tid;
      gload16(ga + (size_t)(slot >> 2) * K + ((slot & 3) << 3), &lds[buf][slot * 8]);
    }
    const short* gb = Bg + (kt << 5);
#pragma unroll
    for (int i = 0; i < BN * 4; i += 256) {
      int slot = i + tid;
      gload16(gb + (size_t)(slot >> 2) * K + ((slot & 3) << 3),
              &lds[buf][BM * 32 + slot * 8]);
    }
  };

  stage(0, 0);
  __syncthreads();
  int cur = 0;
  const int kq = (lane >> 4) << 3;
  const int rr = lane & 15;
  for (int kt = 0; kt < nt; ++kt) {
    if (kt + 1 < nt) stage(kt + 1, cur ^ 1);
    const short* la = &lds[cur][(wm * WM) * 32];
    const short* lb = &lds[cur][BM * 32 + (wn * WN) * 32];
    bf16x8 a[RM], b[RN];
#pragma unroll
    for (int m = 0; m < RM; ++m)
      a[m] = *(const bf16x8*)(la + (m * 16 + rr) * 32 + kq);
#pragma unroll
    for (int n = 0; n < RN; ++n)
      b[n] = *(const bf16x8*)(lb + (n * 16 + rr) * 32 + kq);
#pragma unroll
    for (int m = 0; m < RM; ++m)
#pragma unroll
      for (int n = 0; n < RN; ++n)
        acc[m][n] = __builtin_amdgcn_mfma_f32_16x16x32_bf16(a[m], b[n], acc[m][n], 0, 0, 0);
    __syncthreads();
    cur ^= 1;
  }

  const int rb = row0 + wm * WM + ((lane >> 4) << 2);
  const int cb = col0 + wn * WN + (lane & 15);
#pragma unroll
  for (int m = 0; m < RM; ++m) {
#pragma unroll
    for (int n = 0; n < RN; ++n) {
      const int col = cb + n * 16;
#pragma unroll
      for (int r = 0; r < 4; ++r) {
        const int row = rb + m * 16 + r;
        float v = acc[m][n][r];
        if (EPI == 0) {
          outf[(size_t)row * ldN + col] = v + bias[col];
        } else {
          outf[(size_t)row * (NS_ * D_) + tout * D_ + col] = v + bias[col];
        }
      }
    }
  }
}

// in [R][C] fp32  ->  out [C][R] bf16
__global__ void transpose_cvt(const float* __restrict__ in, short* __restrict__ out,
                              int R, int C) {
  __shared__ float tile[32][33];
  const int tx = threadIdx.x & 31, ty = threadIdx.x >> 5;
  const int c0 = blockIdx.x * 32, r0 = blockIdx.y * 32;
#pragma unroll
  for (int i = 0; i < 32; i += 8)
    tile[ty + i][tx] = in[(size_t)(r0 + ty + i) * C + c0 + tx];
  __syncthreads();
#pragma unroll
  for (int i = 0; i < 32; i += 8)
    out[(size_t)(c0 + ty + i) * R + r0 + tx] = f2bf(tile[tx][ty + i]);
}

__global__ void cvt_bf16_k(const float4* __restrict__ in, short4v* __restrict__ out, int n4) {
  int i = blockIdx.x * 256 + threadIdx.x;
  if (i >= n4) return;
  float4 v = in[i];
  short4v o;
  o[0] = f2bf(v.x); o[1] = f2bf(v.y); o[2] = f2bf(v.z); o[3] = f2bf(v.w);
  out[i] = o;
}

__global__ void tanh_h0_k(const float4* __restrict__ xp, short4v* __restrict__ h, int n4) {
  int i = blockIdx.x * 256 + threadIdx.x;
  if (i >= n4) return;
  float4 v = xp[i];
  short4v o;
  o[0] = f2bf(tanh_fast(v.x)); o[1] = f2bf(tanh_fast(v.y));
  o[2] = f2bf(tanh_fast(v.z)); o[3] = f2bf(tanh_fast(v.w));
  h[i] = o;
}

extern "C" void kernel_launch(void* const* d_in, const int* in_sizes, int n_in,
                              void* d_out, int out_size, void* d_ws, size_t ws_size,
                              hipStream_t stream) {
  const float* z    = (const float*)d_in[0];
  const float* Wx   = (const float*)d_in[1];
  const float* Wh   = (const float*)d_in[2];
  const float* bh   = (const float*)d_in[3];
  const float* Wout = (const float*)d_in[4];
  const float* bout = (const float*)d_in[5];
  float* out = (float*)d_out;

  // workspace layout
  short* zb    = (short*)d_ws;                     // B*D bf16
  short* WxT   = zb + (size_t)B_ * D_;             // [H][D]
  short* WcatT = WxT + (size_t)H_ * D_;            // [H+D][H]  (WhT then WoutT)
  short* WoutT = WcatT + (size_t)H_ * H_;
  short* h0    = WcatT + (size_t)(H_ + D_) * H_;   // [B][H] bf16
  short* h1    = h0 + (size_t)B_ * H_;
  float* xproj = (float*)(h1 + (size_t)B_ * H_);   // [B][H] fp32

  cvt_bf16_k<<<(B_ * D_ / 4 + 255) / 256, 256, 0, stream>>>((const float4*)z, (short4v*)zb, B_ * D_ / 4);
  transpose_cvt<<<dim3(H_ / 32, D_ / 32), 256, 0, stream>>>(Wx, WxT, D_, H_);
  transpose_cvt<<<dim3(H_ / 32, H_ / 32), 256, 0, stream>>>(Wh, WcatT, H_, H_);
  transpose_cvt<<<dim3(D_ / 32, H_ / 32), 256, 0, stream>>>(Wout, WoutT, H_, D_);

  // xproj = z @ Wx + bh
  gemm_bt<128, 128, 0><<<dim3(H_ / 128, B_ / 128), 256, 0, stream>>>(
      zb, WxT, D_, nullptr, bh, xproj, nullptr, H_, 0);
  // h1 = tanh(xproj)
  tanh_h0_k<<<(B_ * H_ / 4 + 255) / 256, 256, 0, stream>>>((const float4*)xproj, (short4v*)h0, B_ * H_ / 4);

  short* hb[2] = {h0, h1};
  for (int t = 1; t <= 15; ++t) {
    const short* hp = hb[(t - 1) & 1];
    short* hn = hb[t & 1];
    // fused: [h_{t+1} | out_{t-1}] = h_t @ [Wh | Wout], 16x10 = 160 blocks
    gemm256_fused<<<160, 512, 0, stream>>>(
        hp, WcatT, H_, xproj, bout, out, hn, t - 1, 10);
  }
  // out_15 = h16 @ Wout + bout
  gemm_bt<128, 64, 2><<<dim3(D_ / 64, B_ / 128), 256, 0, stream>>>(
      hb[1], WoutT, H_, nullptr, bout, out, nullptr, 0, 15);
}

// Round 5
// 1220.170 us; speedup vs baseline: 1.2487x; 1.2359x over previous
//
#include <hip/hip_runtime.h>
#include <hip/hip_bf16.h>
#include <stdint.h>

#define B_ 4096
#define D_ 512
#define H_ 2048
#define NS_ 16

typedef __bf16 bf16x8 __attribute__((ext_vector_type(8)));
typedef float f32x4 __attribute__((ext_vector_type(4)));
typedef short short4v __attribute__((ext_vector_type(4)));
typedef __attribute__((address_space(3))) const bf16x8* lds_frag_p;

__device__ __forceinline__ short f2bf(float f) {
  union { float f; uint32_t u; } c; c.f = f;
  uint32_t u = c.u;
  return (short)((u + 0x7fffu + ((u >> 16) & 1u)) >> 16);
}

__device__ __forceinline__ float tanh_fast(float x) {
  float e = __expf(2.0f * x);
  return 1.0f - 2.0f / (e + 1.0f);   // exp overflow -> 1, underflow -> -1 : safe
}

__device__ __forceinline__ void gload16(const void* g, void* l) {
  __builtin_amdgcn_global_load_lds((const __attribute__((address_space(1))) void*)g,
                                   (__attribute__((address_space(3))) void*)l,
                                   16, 0, 0);
}

// ===========================================================================
// Fused RNN step GEMM: 128x128 tile, 4 waves (2x2, wave-tile 64x64), BK=32,
// 3-deep LDS ring (48 KB -> 3 blocks/CU), counted vmcnt(4), stage-at-top,
// T2 XOR swizzle (0 bank conflicts), XCD-swizzled 640-block grid (full chip).
//   [h_next | out_t] = tanh(xproj + h @ Wh) | (h @ Wout + bout)
// A  = h_t     [4096][2048] bf16 row-major
// Bt = Wcat^T  [2560][2048] bf16 row-major (rows = output cols)
// ===========================================================================
__global__ __launch_bounds__(256, 3) void gemm128_fused(
    const short* __restrict__ A, const short* __restrict__ Bt, int K,
    const float* __restrict__ xproj, const float* __restrict__ bias,
    float* __restrict__ outf, short* __restrict__ outh, int tout, int gridN)
{
  __shared__ short lds[3 * 8192];             // 48 KB: 3 bufs x (A 4096 + B 4096 shorts)
  const int tid = threadIdx.x, lane = tid & 63, wid = tid >> 6;
  const int wm = wid >> 1, wn = wid & 1;      // 2x2 waves, wave tile 64x64

  // XCD-aware bijective swizzle (gridDim.x % 8 == 0)
  const int nwg = gridDim.x;
  const int cpx = nwg >> 3;
  const int swz = ((int)blockIdx.x & 7) * cpx + ((int)blockIdx.x >> 3);
  const int tm = swz / gridN, tn = swz % gridN;
  const int row0 = tm * 128, col0 = tn * 128;

  const int NT = K >> 5;                      // K-tiles of 32

  // ---- staging: global source carries the inverse XOR swizzle (rule 21) ----
  // One wave-instr covers 16 rows x 64 B, lane-linear LDS dest.
  const int r0 = wid * 16 + (lane >> 2);      // sweep 0: rows 0..63
  const int r1 = r0 + 64;                     // sweep 1: rows 64..127
  const int sl = lane & 3;
  const short* gA0 = A  + (size_t)(row0 + r0) * K + ((sl ^ ((r0 >> 1) & 3)) << 3);
  const short* gA1 = A  + (size_t)(row0 + r1) * K + ((sl ^ ((r1 >> 1) & 3)) << 3);
  const short* gB0 = Bt + (size_t)(col0 + r0) * K + ((sl ^ ((r0 >> 1) & 3)) << 3);
  const short* gB1 = Bt + (size_t)(col0 + r1) * K + ((sl ^ ((r1 >> 1) & 3)) << 3);
  const int dls = (wid * 16 + (lane >> 2)) * 32 + (lane & 3) * 8;  // lane-linear

  // ---- fragment read offsets (element units, swizzled) ----
  const int rr = lane & 15, s4 = lane >> 4;
  int offA[4], offB[4];
#pragma unroll
  for (int m = 0; m < 4; ++m) {
    int r = wm * 64 + m * 16 + rr;
    offA[m] = r * 32 + ((s4 ^ ((r >> 1) & 3)) << 3);
  }
#pragma unroll
  for (int n = 0; n < 4; ++n) {
    int r = wn * 64 + n * 16 + rr;
    offB[n] = 4096 + r * 32 + ((s4 ^ ((r >> 1) & 3)) << 3);
  }

  f32x4 acc[4][4];
#pragma unroll
  for (int m = 0; m < 4; ++m)
#pragma unroll
    for (int n = 0; n < 4; ++n)
      acc[m][n] = (f32x4){0.f, 0.f, 0.f, 0.f};

  auto stage = [&](int kt, int base) {
    const size_t ko = (size_t)kt * 32;
    gload16(gA0 + ko, &lds[base + dls]);
    gload16(gA1 + ko, &lds[base + 2048 + dls]);
    gload16(gB0 + ko, &lds[base + 4096 + dls]);
    gload16(gB1 + ko, &lds[base + 6144 + dls]);
  };

  // prologue: stage tiles 0,1 (8 loads)
  stage(0, 0);
  stage(1, 8192);
  asm volatile("s_waitcnt vmcnt(4)" ::: "memory");   // tile 0 landed (own loads)
  __builtin_amdgcn_s_barrier();                      // all waves' tile-0 landed

  int cur = 0, stb = 2;
  for (int kt = 0; kt < NT; ++kt) {
    const bool st = (kt + 2 < NT);
    if (st) {
      stage(kt + 2, stb * 8192);                     // top: max age before wait
      stb = (stb == 2) ? 0 : stb + 1;
    }
    const int bb = cur * 8192;

    bf16x8 a[4], b[4];
#pragma unroll
    for (int m = 0; m < 4; ++m) a[m] = *(lds_frag_p)&lds[bb + offA[m]];
#pragma unroll
    for (int n = 0; n < 4; ++n) b[n] = *(lds_frag_p)&lds[bb + offB[n]];

#pragma unroll
    for (int m = 0; m < 4; ++m)
#pragma unroll
      for (int n = 0; n < 4; ++n)
        acc[m][n] = __builtin_amdgcn_mfma_f32_16x16x32_bf16(a[m], b[n], acc[m][n], 0, 0, 0);

    if (st) {
      asm volatile("s_waitcnt vmcnt(4)" ::: "memory");   // tile kt+1 landed
    } else if (kt == NT - 2) {
      asm volatile("s_waitcnt vmcnt(0)" ::: "memory");
    }
    if (kt < NT - 1) __builtin_amdgcn_s_barrier();
    cur = (cur == 2) ? 0 : cur + 1;
  }

  // ---- epilogue: C/D layout col = lane&15, row = (lane>>4)*4 + reg ----
  const int rb = row0 + wm * 64 + ((lane >> 4) << 2);
  const int cb = col0 + wn * 64 + (lane & 15);
#pragma unroll
  for (int m = 0; m < 4; ++m) {
#pragma unroll
    for (int n = 0; n < 4; ++n) {
      const int col = cb + n * 16;
#pragma unroll
      for (int r = 0; r < 4; ++r) {
        const int row = rb + m * 16 + r;
        float v = acc[m][n][r];
        if (col < H_) {
          float x = xproj[(size_t)row * H_ + col];
          outh[(size_t)row * H_ + col] = f2bf(tanh_fast(x + v));
        } else {
          int oc = col - H_;
          outf[(size_t)row * (NS_ * D_) + tout * D_ + oc] = v + bias[oc];
        }
      }
    }
  }
}

// ---------------------------------------------------------------------------
// 128-tile GEMM (round-1 structure) for xproj (EPI 0) and final out (EPI 2).
// ---------------------------------------------------------------------------
template<int BM, int BN, int EPI>
__global__ __launch_bounds__(256, 2) void gemm_bt(
    const short* __restrict__ A, const short* __restrict__ Bt, int K,
    const float* __restrict__ xproj, const float* __restrict__ bias,
    float* __restrict__ outf, short* __restrict__ outh, int ldN, int tout)
{
  constexpr int WM = BM / 2, WN = BN / 2;
  constexpr int RM = WM / 16, RN = WN / 16;
  __shared__ short lds[2][(BM + BN) * 32];
  const int tid = threadIdx.x, lane = tid & 63, wid = tid >> 6;
  const int wm = wid >> 1, wn = wid & 1;
  const int row0 = blockIdx.y * BM, col0 = blockIdx.x * BN;
  const short* Ag = A + (size_t)row0 * K;
  const short* Bg = Bt + (size_t)col0 * K;

  f32x4 acc[RM][RN];
#pragma unroll
  for (int m = 0; m < RM; ++m)
#pragma unroll
    for (int n = 0; n < RN; ++n)
      acc[m][n] = (f32x4){0.f, 0.f, 0.f, 0.f};

  const int nt = K >> 5;

  auto stage = [&](int kt, int buf) {
    const short* ga = Ag + (kt << 5);
#pragma unroll
    for (int i = 0; i < BM * 4; i += 256) {
      int slot = i + tid;
      gload16(ga + (size_t)(slot >> 2) * K + ((slot & 3) << 3), &lds[buf][slot * 8]);
    }
    const short* gb = Bg + (kt << 5);
#pragma unroll
    for (int i = 0; i < BN * 4; i += 256) {
      int slot = i + tid;
      gload16(gb + (size_t)(slot >> 2) * K + ((slot & 3) << 3),
              &lds[buf][BM * 32 + slot * 8]);
    }
  };

  stage(0, 0);
  __syncthreads();
  int cur = 0;
  const int kq = (lane >> 4) << 3;
  const int rr = lane & 15;
  for (int kt = 0; kt < nt; ++kt) {
    if (kt + 1 < nt) stage(kt + 1, cur ^ 1);
    const short* la = &lds[cur][(wm * WM) * 32];
    const short* lb = &lds[cur][BM * 32 + (wn * WN) * 32];
    bf16x8 a[RM], b[RN];
#pragma unroll
    for (int m = 0; m < RM; ++m)
      a[m] = *(const bf16x8*)(la + (m * 16 + rr) * 32 + kq);
#pragma unroll
    for (int n = 0; n < RN; ++n)
      b[n] = *(const bf16x8*)(lb + (n * 16 + rr) * 32 + kq);
#pragma unroll
    for (int m = 0; m < RM; ++m)
#pragma unroll
      for (int n = 0; n < RN; ++n)
        acc[m][n] = __builtin_amdgcn_mfma_f32_16x16x32_bf16(a[m], b[n], acc[m][n], 0, 0, 0);
    __syncthreads();
    cur ^= 1;
  }

  const int rb = row0 + wm * WM + ((lane >> 4) << 2);
  const int cb = col0 + wn * WN + (lane & 15);
#pragma unroll
  for (int m = 0; m < RM; ++m) {
#pragma unroll
    for (int n = 0; n < RN; ++n) {
      const int col = cb + n * 16;
#pragma unroll
      for (int r = 0; r < 4; ++r) {
        const int row = rb + m * 16 + r;
        float v = acc[m][n][r];
        if (EPI == 0) {
          outf[(size_t)row * ldN + col] = v + bias[col];
        } else {
          outf[(size_t)row * (NS_ * D_) + tout * D_ + col] = v + bias[col];
        }
      }
    }
  }
}

// in [R][C] fp32  ->  out [C][R] bf16
__global__ void transpose_cvt(const float* __restrict__ in, short* __restrict__ out,
                              int R, int C) {
  __shared__ float tile[32][33];
  const int tx = threadIdx.x & 31, ty = threadIdx.x >> 5;
  const int c0 = blockIdx.x * 32, r0 = blockIdx.y * 32;
#pragma unroll
  for (int i = 0; i < 32; i += 8)
    tile[ty + i][tx] = in[(size_t)(r0 + ty + i) * C + c0 + tx];
  __syncthreads();
#pragma unroll
  for (int i = 0; i < 32; i += 8)
    out[(size_t)(c0 + ty + i) * R + r0 + tx] = f2bf(tile[tx][ty + i]);
}

__global__ void cvt_bf16_k(const float4* __restrict__ in, short4v* __restrict__ out, int n4) {
  int i = blockIdx.x * 256 + threadIdx.x;
  if (i >= n4) return;
  float4 v = in[i];
  short4v o;
  o[0] = f2bf(v.x); o[1] = f2bf(v.y); o[2] = f2bf(v.z); o[3] = f2bf(v.w);
  out[i] = o;
}

__global__ void tanh_h0_k(const float4* __restrict__ xp, short4v* __restrict__ h, int n4) {
  int i = blockIdx.x * 256 + threadIdx.x;
  if (i >= n4) return;
  float4 v = xp[i];
  short4v o;
  o[0] = f2bf(tanh_fast(v.x)); o[1] = f2bf(tanh_fast(v.y));
  o[2] = f2bf(tanh_fast(v.z)); o[3] = f2bf(tanh_fast(v.w));
  h[i] = o;
}

extern "C" void kernel_launch(void* const* d_in, const int* in_sizes, int n_in,
                              void* d_out, int out_size, void* d_ws, size_t ws_size,
                              hipStream_t stream) {
  const float* z    = (const float*)d_in[0];
  const float* Wx   = (const float*)d_in[1];
  const float* Wh   = (const float*)d_in[2];
  const float* bh   = (const float*)d_in[3];
  const float* Wout = (const float*)d_in[4];
  const float* bout = (const float*)d_in[5];
  float* out = (float*)d_out;

  // workspace layout
  short* zb    = (short*)d_ws;                     // B*D bf16
  short* WxT   = zb + (size_t)B_ * D_;             // [H][D]
  short* WcatT = WxT + (size_t)H_ * D_;            // [H+D][H]  (WhT then WoutT)
  short* WoutT = WcatT + (size_t)H_ * H_;
  short* h0    = WcatT + (size_t)(H_ + D_) * H_;   // [B][H] bf16
  short* h1    = h0 + (size_t)B_ * H_;
  float* xproj = (float*)(h1 + (size_t)B_ * H_);   // [B][H] fp32

  cvt_bf16_k<<<(B_ * D_ / 4 + 255) / 256, 256, 0, stream>>>((const float4*)z, (short4v*)zb, B_ * D_ / 4);
  transpose_cvt<<<dim3(H_ / 32, D_ / 32), 256, 0, stream>>>(Wx, WxT, D_, H_);
  transpose_cvt<<<dim3(H_ / 32, H_ / 32), 256, 0, stream>>>(Wh, WcatT, H_, H_);
  transpose_cvt<<<dim3(D_ / 32, H_ / 32), 256, 0, stream>>>(Wout, WoutT, H_, D_);

  // xproj = z @ Wx + bh
  gemm_bt<128, 128, 0><<<dim3(H_ / 128, B_ / 128), 256, 0, stream>>>(
      zb, WxT, D_, nullptr, bh, xproj, nullptr, H_, 0);
  // h1 = tanh(xproj)
  tanh_h0_k<<<(B_ * H_ / 4 + 255) / 256, 256, 0, stream>>>((const float4*)xproj, (short4v*)h0, B_ * H_ / 4);

  short* hb[2] = {h0, h1};
  for (int t = 1; t <= 15; ++t) {
    const short* hp = hb[(t - 1) & 1];
    short* hn = hb[t & 1];
    // fused: [h_{t+1} | out_{t-1}] = h_t @ [Wh | Wout], 32x20 = 640 blocks
    gemm128_fused<<<640, 256, 0, stream>>>(
        hp, WcatT, H_, xproj, bout, out, hn, t - 1, 20);
  }
  // out_15 = h16 @ Wout + bout
  gemm_bt<128, 64, 2><<<dim3(D_ / 64, B_ / 128), 256, 0, stream>>>(
      hb[1], WoutT, H_, nullptr, bout, out, nullptr, 0, 15);
}